// Round 10
// baseline (588.827 us; speedup 1.0000x reference)
//
#include <hip/hip_runtime.h>
#include <stdint.h>

typedef __attribute__((ext_vector_type(8))) short short8;
typedef __attribute__((ext_vector_type(4))) float f32x4;

// ---- problem constants ----
#define TOKENS 4096
#define DDIM 1024
#define IDIM 512
#define NEXP 16
#define NEXP1 17
#define CSTRIDE 32    // counts padded: one counter per 128 B
#define MAXMB 112     // max total m-blocks: 32 (shared) + sum ceil(cnt/128) <= 112

// ---- workspace layout (bytes) ----
#define OFF_WGU   0ull           // 17*1024*1024*2   [e][n'(interleaved 2i+{g,u})][k] bf16
#define OFF_WD    35651584ull    // 17*1024*512*2    [e][n(D)][k(I)] bf16
#define OFF_XB    53477376ull    // 4096*1024*2      x in bf16
#define OFF_HGU   61865984ull    // 12288*1024*2     gemmB out
#define OFF_H     87031808ull    // 12288*512*2      silu(g)*u
#define OFF_TOK   99614720ull    // 17*4096*4
#define OFF_REC   99893248ull    // 4096*8
#define OFF_WREC  99926016ull    // 4096*8
#define OFF_MYTAB 99958784ull    // 112*16 per-m-block (e,m0,base,cnt) table (in old gap)
#define OFF_CNT   100171776ull   // 17*128 padded counters + ticket @int768 (4096 B zeroed)
#define OFF_BASE  100175872ull   // bases[20] (combine uses); mbp now LDS-only

#define TICKET_IDX 768           // int index inside counts region (byte 3072, zeroed)

__device__ __forceinline__ float bf2f(unsigned short u) {
    union { uint32_t i; float f; } v; v.i = ((uint32_t)u) << 16; return v.f;
}
__device__ __forceinline__ unsigned short f2bf(float f) {
    union { float f; uint32_t i; } v; v.f = f;
    uint32_t r = v.i + 0x7FFFu + ((v.i >> 16) & 1u);  // RNE
    return (unsigned short)(r >> 16);
}
// async 16B global->LDS (dest = wave-uniform base + lane*16). imm offset ALWAYS 0.
__device__ __forceinline__ void cp16(const unsigned short* g, unsigned short* l) {
    __builtin_amdgcn_global_load_lds(
        (const __attribute__((address_space(1))) uint32_t*)g,
        (__attribute__((address_space(3))) uint32_t*)l, 16, 0, 0);
}

// ==== merged front: 256-thread blocks (round-7 lesson: keep transpose's shape).
//      blocks [0,1024): router (4 waves / 4 tokens) + fused xconv
//      blocks [1024,7552): weight transpose, round-0 verbatim body
//      + ticket prefix: winner block builds bases[] and the mytab[] m-block table.
//      LDS union = 20.5 KB -> 7 blocks/CU for both roles. ====
__global__ __launch_bounds__(256)
void k_front(const float* __restrict__ x, const float* __restrict__ gw,
             const float* __restrict__ gb,
             const float* __restrict__ eg, const float* __restrict__ eu,
             const float* __restrict__ ed, const float* __restrict__ sg,
             const float* __restrict__ su, const float* __restrict__ sd,
             unsigned short* __restrict__ Wgu, unsigned short* __restrict__ Wd,
             unsigned short* __restrict__ xb, int* __restrict__ tok,
             int2* __restrict__ rec, float2* __restrict__ wrec,
             int* __restrict__ counts, int* __restrict__ bases,
             int4* __restrict__ mytab)
{
    __shared__ union {
        float gws[1024 * 5];     // router staging, stride 5 (gcd(5,32)=1: conflict-free)
        float tl[64 * 65];       // transpose tile
    } sm;
    __shared__ int pfx[40];      // winner block: bases in [0..17], mbp in [20..37]
    __shared__ int winflag;

    const int bid = blockIdx.x;
    const int tid = threadIdx.x;

    if (bid < 1024) {
        // ================= router block: 4 tokens, 1/wave =================
        {   // fused xconv: this block's 4 token rows (1024 float4 groups)
            const int b0 = bid * 1024;
            #pragma unroll
            for (int c = 0; c < 4; ++c) {
                int i = b0 + c * 256 + tid;
                float4 v4 = ((const float4*)x)[i];
                ushort4 b;
                b.x = f2bf(v4.x); b.y = f2bf(v4.y); b.z = f2bf(v4.z); b.w = f2bf(v4.w);
                ((ushort4*)xb)[i] = b;
            }
            if (tid < 4) tok[16 * 4096 + bid * 4 + tid] = bid * 4 + tid;
        }

        const int t = bid * 4 + (tid >> 6);
        const int lane = tid & 63;
        const float* xr = x + (size_t)t * DDIM;

        float xv[16];
        #pragma unroll
        for (int kk = 0; kk < 16; ++kk) xv[kk] = xr[kk * 64 + lane];

        float v[16];
        for (int p = 0; p < 4; ++p) {            // 4 experts per phase
            __syncthreads();
            #pragma unroll
            for (int c = 0; c < 4; ++c) {
                int k = tid + c * 256;           // 0..1023
                float4 g4 = *(const float4*)(gw + k * 16 + p * 4);
                float* d = &sm.gws[k * 5];
                d[0] = g4.x; d[1] = g4.y; d[2] = g4.z; d[3] = g4.w;
            }
            __syncthreads();

            double a[4] = {0.0, 0.0, 0.0, 0.0};
            #pragma unroll
            for (int kk = 0; kk < 16; ++kk) {
                int kl = kk * 64 + lane;
                double xd = (double)xv[kk];
                const float* g = &sm.gws[kl * 5];
                a[0] += xd * (double)g[0];
                a[1] += xd * (double)g[1];
                a[2] += xd * (double)g[2];
                a[3] += xd * (double)g[3];
            }
            #pragma unroll
            for (int off = 32; off > 0; off >>= 1) {
                #pragma unroll
                for (int j = 0; j < 4; ++j)
                    a[j] += __shfl_xor(a[j], off, 64);
            }
            #pragma unroll
            for (int j = 0; j < 4; ++j)
                v[p * 4 + j] = 1.0f / (1.0f + expf(-(float)(a[j] + (double)gb[p * 4 + j])));
        }

        if (lane == 0) {
            int i0 = 0;
            #pragma unroll
            for (int e = 1; e < 16; ++e) if (v[e] > v[i0]) i0 = e;
            int i1 = (i0 == 0) ? 1 : 0;
            #pragma unroll
            for (int e = 0; e < 16; ++e) if (e != i0 && e != i1 && v[e] > v[i1]) i1 = e;
            float s = v[i0] + v[i1];
            float w0 = v[i0] / s, w1 = v[i1] / s;
            int p0 = atomicAdd(&counts[i0 * CSTRIDE], 1);
            tok[i0 * 4096 + p0] = t;
            int p1 = atomicAdd(&counts[i1 * CSTRIDE], 1);
            tok[i1 * 4096 + p1] = t;
            rec[t]  = make_int2(i0 * 4096 + p0, i1 * 4096 + p1);
            wrec[t] = make_float2(w0, w1);
        }
    } else {
        // ================= transpose: one 64x64 tile (round-0 body) =================
        const int tau = bid - 1024;              // 0..6527
        const int z = tau >> 7, rem = tau & 127;
        const int e = z / 3, m = z % 3;
        int ty, tx;
        if (m == 2) { ty = rem >> 4; tx = rem & 15; }
        else        { ty = rem >> 3; tx = rem & 7;  }
        const int C = (m == 2) ? 1024 : 512;
        const int r0 = ty * 64, c0 = tx * 64;
        const float* src;
        if (m == 0)      src = (e < 16) ? eg + (size_t)e * 524288 : sg;
        else if (m == 1) src = (e < 16) ? eu + (size_t)e * 524288 : su;
        else             src = (e < 16) ? ed + (size_t)e * 524288 : sd;

        {
            const int lr = tid >> 4;
            const int lc = (tid & 15) * 4;
            #pragma unroll
            for (int ps = 0; ps < 4; ++ps) {
                int r = ps * 16 + lr;
                float4 vv = *(const float4*)(src + (size_t)(r0 + r) * C + (c0 + lc));
                float* d = &sm.tl[r * 65 + lc];
                d[0] = vv.x; d[1] = vv.y; d[2] = vv.z; d[3] = vv.w;
            }
        }
        __syncthreads();
        {
            const int w = tid >> 6, l = tid & 63;
            const int kb = (l & 7) * 8;
            #pragma unroll
            for (int p = 0; p < 2; ++p) {
                int nl = p * 32 + w * 8 + (l >> 3);
                unsigned short ov[8];
                #pragma unroll
                for (int j = 0; j < 8; ++j)
                    ov[j] = f2bf(sm.tl[(kb + j) * 65 + nl]);
                int n = c0 + nl;
                int k = r0 + kb;
                unsigned short* dst;
                if (m < 2) dst = Wgu + (size_t)e * 1048576 + (size_t)(2 * n + m) * 1024 + k;
                else       dst = Wd  + (size_t)e * 524288  + (size_t)n * 512 + k;
                *(uint4*)dst = *(uint4*)ov;
            }
        }
    }

    // ---- ticket: last-finishing block builds bases + mytab (parallel fill) ----
    __syncthreads();
    if (tid == 0) {
        __threadfence();
        winflag = (atomicAdd(&counts[TICKET_IDX], 1) == (int)gridDim.x - 1) ? 1 : 0;
    }
    __syncthreads();
    if (winflag) {
        if (tid == 0) {
            int a = 0, b = 0;
            for (int e2 = 0; e2 < NEXP1; ++e2) {
                int c = (e2 < 16) ? atomicAdd(&counts[e2 * CSTRIDE], 0) : TOKENS;
                pfx[e2] = a; pfx[20 + e2] = b;
                bases[e2] = a;                   // combine needs global bases
                a += c; b += (c + 127) >> 7;
            }
            pfx[17] = a; pfx[37] = b;
            bases[17] = a;
        }
        __syncthreads();
        const int nmb = pfx[37];
        for (int idx = tid; idx < MAXMB; idx += 256) {
            int4 val = make_int4(0, 0, 0, 0);    // cnt=0,m0=0 -> gemm exits
            if (idx < nmb) {
                int e2 = 0;
                #pragma unroll
                for (int i2 = 1; i2 <= 16; ++i2)
                    if (idx >= pfx[20 + i2]) e2 = i2;
                val = make_int4(e2, (idx - pfx[20 + e2]) * 128,
                                pfx[e2], pfx[e2 + 1] - pfx[e2]);
            }
            mytab[idx] = val;
        }
    }
}

// ---- grouped GEMM: round-0 core (best measured) + one-load mytab lookup
//      (replaces serial 17-iter dependent-load search) + bijective XCD swizzle
//      (all 8 N-blocks of an m-block on one XCD -> A-tile L2 reuse) + verified
//      zero-conflict seg swizzle (rounds 2/5: 3.4M -> 0 conflict cycles). ----
// MODE 0: A = xb gathered, K=1024, B = Wgu interleaved -> fused silu -> H (bf16)
// MODE 1: A = H (contiguous slots), K=512, B = Wd -> Hgu (bf16)
template <int MODE>
__global__ __launch_bounds__(256, 3)
void k_gemm(const unsigned short* __restrict__ Amat, const unsigned short* __restrict__ Bmat,
            const int* __restrict__ tok, const int4* __restrict__ mytab,
            unsigned short* __restrict__ Out)
{
    constexpr int K = (MODE == 0) ? 1024 : 512;
    // XCD swizzle: lin%8 = XCD; give each XCD 14 consecutive m-blocks, all 8 N each.
    const int lin = blockIdx.x;                     // 0..895 (8*112)
    const int wg  = (lin & 7) * MAXMB + (lin >> 3);
    const int my  = wg >> 3;
    const int n0  = (wg & 7) * 128;
    const int4 tt = mytab[my];
    const int e = tt.x, m0 = tt.y, base = tt.z, cnt = tt.w;
    if (m0 >= cnt) return;

    __shared__ unsigned short As0[128 * 32];   // k-half 0 (8 KB each, 64-B rows)
    __shared__ unsigned short As1[128 * 32];   // k-half 1
    __shared__ unsigned short Bs0[128 * 32];
    __shared__ unsigned short Bs1[128 * 32];

    const int tid  = threadIdx.x;
    const int wave = tid >> 6;
    const int lane = tid & 63;
    const int lrow = lane >> 2;                          // 0..15
    const int lseg = (lane & 3) ^ ((lrow >> 1) & 3);     // swizzled source 16B segment

    unsigned short* a0d0 = &As0[wave * 1024];
    unsigned short* a0d1 = &As0[wave * 1024 + 512];
    unsigned short* a1d0 = &As1[wave * 1024];
    unsigned short* a1d1 = &As1[wave * 1024 + 512];
    unsigned short* b0d0 = &Bs0[wave * 1024];
    unsigned short* b0d1 = &Bs0[wave * 1024 + 512];
    unsigned short* b1d0 = &Bs1[wave * 1024];
    unsigned short* b1d1 = &Bs1[wave * 1024 + 512];

    int ar0 = m0 + wave * 32 + lrow;      if (ar0 > cnt - 1) ar0 = cnt - 1;
    int ar1 = m0 + wave * 32 + 16 + lrow; if (ar1 > cnt - 1) ar1 = cnt - 1;
    size_t ai0, ai1;
    if (MODE == 0) { ai0 = (size_t)tok[e * 4096 + ar0]; ai1 = (size_t)tok[e * 4096 + ar1]; }
    else           { ai0 = (size_t)(base + ar0);        ai1 = (size_t)(base + ar1); }
    const unsigned short* ag0 = Amat + ai0 * K + lseg * 8;
    const unsigned short* ag1 = Amat + ai1 * K + lseg * 8;
    const size_t eoff = (size_t)e * 1024 * K;
    const unsigned short* bg0 = Bmat + eoff + (size_t)(n0 + wave * 32 + lrow) * K + lseg * 8;
    const unsigned short* bg1 = Bmat + eoff + (size_t)(n0 + wave * 32 + 16 + lrow) * K + lseg * 8;

    const int wm = wave & 1, wn = wave >> 1;
    const int q = lane >> 4, mc = lane & 15;
    const int qs = (q ^ ((mc >> 1) & 3)) * 8;            // swizzled read seg (elems)

    f32x4 acc[4][4];
    #pragma unroll
    for (int i = 0; i < 4; ++i)
        #pragma unroll
        for (int j = 0; j < 4; ++j) acc[i][j] = (f32x4){0.f, 0.f, 0.f, 0.f};

    for (int k0 = 0; k0 < K; k0 += 64) {
        __syncthreads();
        cp16(ag0 + k0,      a0d0);
        cp16(ag0 + k0 + 32, a1d0);
        cp16(ag1 + k0,      a0d1);
        cp16(ag1 + k0 + 32, a1d1);
        cp16(bg0 + k0,      b0d0);
        cp16(bg0 + k0 + 32, b1d0);
        cp16(bg1 + k0,      b0d1);
        cp16(bg1 + k0 + 32, b1d1);
        __syncthreads();
        short8 a0[4], b0[4], a1[4], b1[4];
        #pragma unroll
        for (int i = 0; i < 4; ++i) {
            a0[i] = *(const short8*)&As0[(wm * 64 + i * 16 + mc) * 32 + qs];
            a1[i] = *(const short8*)&As1[(wm * 64 + i * 16 + mc) * 32 + qs];
        }
        #pragma unroll
        for (int j = 0; j < 4; ++j) {
            b0[j] = *(const short8*)&Bs0[(wn * 64 + j * 16 + mc) * 32 + qs];
            b1[j] = *(const short8*)&Bs1[(wn * 64 + j * 16 + mc) * 32 + qs];
        }
        #pragma unroll
        for (int i = 0; i < 4; ++i)
            #pragma unroll
            for (int j = 0; j < 4; ++j)
                acc[i][j] = __builtin_amdgcn_mfma_f32_16x16x32_bf16(a0[i], b0[j], acc[i][j], 0, 0, 0);
        #pragma unroll
        for (int i = 0; i < 4; ++i)
            #pragma unroll
            for (int j = 0; j < 4; ++j)
                acc[i][j] = __builtin_amdgcn_mfma_f32_16x16x32_bf16(a1[i], b1[j], acc[i][j], 0, 0, 0);
    }

    // epilogue: C/D layout col=lane&15, row=(lane>>4)*4+reg  [m89-verified]
    #pragma unroll
    for (int i = 0; i < 4; ++i) {
        int lr = wm * 64 + i * 16 + q * 4;
        #pragma unroll
        for (int r = 0; r < 4; ++r) {
            int mrow = m0 + lr + r;
            if (mrow >= cnt) continue;
            #pragma unroll
            for (int j = 0; j < 4; ++j) {
                int gc = n0 + wn * 64 + j * 16 + mc;
                float val = acc[i][j][r];
                if (MODE == 0) {
                    float other = __shfl_xor(val, 1, 64);
                    float g = (mc & 1) ? other : val;
                    float u = (mc & 1) ? val : other;
                    float h = g / (1.0f + __expf(-g)) * u;
                    if ((mc & 1) == 0)
                        Out[(size_t)(base + mrow) * 512 + (gc >> 1)] = f2bf(h);
                } else {
                    Out[(size_t)(base + mrow) * 1024 + gc] = f2bf(val);
                }
            }
        }
    }
}

// ---- out[t] = x[t] + Hs[shared] + w0*Hs[s0] + w1*Hs[s1] ----
__global__ void k_combine(const float* __restrict__ x, const unsigned short* __restrict__ Hs,
                          const int2* __restrict__ rec, const float2* __restrict__ wrec,
                          const int* __restrict__ bases, float* __restrict__ out)
{
    int t = blockIdx.x * 2 + (threadIdx.x >> 7);
    int c = (threadIdx.x & 127) * 8;
    int2 r = rec[t];
    float2 w = wrec[t];
    int s0 = bases[r.x >> 12] + (r.x & 4095);
    int s1 = bases[r.y >> 12] + (r.y & 4095);
    int ss = 8192 + t;

    unsigned short h0[8], h1[8], hs[8];
    *(uint4*)h0 = *(const uint4*)(Hs + (size_t)s0 * 1024 + c);
    *(uint4*)h1 = *(const uint4*)(Hs + (size_t)s1 * 1024 + c);
    *(uint4*)hs = *(const uint4*)(Hs + (size_t)ss * 1024 + c);
    const float* xr = x + (size_t)t * 1024 + c;
    float o[8];
    #pragma unroll
    for (int j = 0; j < 8; ++j)
        o[j] = xr[j] + bf2f(hs[j]) + w.x * bf2f(h0[j]) + w.y * bf2f(h1[j]);
    float* orow = out + (size_t)t * 1024 + c;
    *(float4*)orow       = *(float4*)&o[0];
    *(float4*)(orow + 4) = *(float4*)&o[4];
}

extern "C" void kernel_launch(void* const* d_in, const int* in_sizes, int n_in,
                              void* d_out, int out_size, void* d_ws, size_t ws_size,
                              hipStream_t stream)
{
    const float* x  = (const float*)d_in[0];
    const float* gw = (const float*)d_in[1];
    const float* gb = (const float*)d_in[2];
    const float* sg = (const float*)d_in[3];
    const float* su = (const float*)d_in[4];
    const float* sd = (const float*)d_in[5];
    const float* eg = (const float*)d_in[6];
    const float* eu = (const float*)d_in[7];
    const float* ed = (const float*)d_in[8];
    float* out = (float*)d_out;
    char* ws = (char*)d_ws;

    unsigned short* Wgu = (unsigned short*)(ws + OFF_WGU);
    unsigned short* Wd  = (unsigned short*)(ws + OFF_WD);
    unsigned short* xb  = (unsigned short*)(ws + OFF_XB);
    unsigned short* Hgu = (unsigned short*)(ws + OFF_HGU);
    unsigned short* H   = (unsigned short*)(ws + OFF_H);
    int*    tok   = (int*)(ws + OFF_TOK);
    int2*   rec   = (int2*)(ws + OFF_REC);
    float2* wrec  = (float2*)(ws + OFF_WREC);
    int4*   mytab = (int4*)(ws + OFF_MYTAB);
    int*    counts= (int*)(ws + OFF_CNT);
    int*    bases = (int*)(ws + OFF_BASE);

    (void)hipMemsetAsync(counts, 0, 4096, stream);
    k_front<<<7552, 256, 0, stream>>>(x, gw, gb, eg, eu, ed, sg, su, sd,
                                      Wgu, Wd, xb, tok, rec, wrec, counts, bases, mytab);
    k_gemm<0><<<8 * MAXMB, 256, 0, stream>>>(xb, Wgu, tok, mytab, H);
    k_gemm<1><<<8 * MAXMB, 256, 0, stream>>>(H, Wd, tok, mytab, Hgu);
    k_combine<<<2048, 256, 0, stream>>>(x, Hgu, rec, wrec, bases, out);
}

// Round 11
// 287.591 us; speedup vs baseline: 2.0474x; 2.0474x over previous
//
#include <hip/hip_runtime.h>
#include <stdint.h>

typedef __attribute__((ext_vector_type(8))) short short8;
typedef __attribute__((ext_vector_type(4))) float f32x4;

// ---- problem constants ----
#define TOKENS 4096
#define DDIM 1024
#define IDIM 512
#define NEXP 16
#define NEXP1 17
#define CSTRIDE 32    // counts padded: one counter per 128 B
#define MAXMB 112     // max total m-blocks: 32 (shared) + sum ceil(cnt/128) <= 112

// ---- workspace layout (bytes) ----
#define OFF_WGU   0ull           // 17*1024*1024*2   [e][n'(interleaved 2i+{g,u})][k] bf16
#define OFF_WD    35651584ull    // 17*1024*512*2    [e][n(D)][k(I)] bf16
#define OFF_XB    53477376ull    // 4096*1024*2      x in bf16
#define OFF_HGU   61865984ull    // 12288*1024*2     gemmB out
#define OFF_H     87031808ull    // 12288*512*2      silu(g)*u
#define OFF_TOK   99614720ull    // 17*4096*4
#define OFF_REC   99893248ull    // 4096*8
#define OFF_WREC  99926016ull    // 4096*8
#define OFF_MYTAB 99958784ull    // 112*16 per-m-block (e,m0,base,cnt) table
#define OFF_CNT   100171776ull   // 17*128 padded counters + ticket @int768 (4096 B zeroed)
#define OFF_BASE  100175872ull   // bases[20] (combine uses)

#define TICKET_IDX 768           // int index inside counts region (byte 3072, zeroed)

__device__ __forceinline__ float bf2f(unsigned short u) {
    union { uint32_t i; float f; } v; v.i = ((uint32_t)u) << 16; return v.f;
}
__device__ __forceinline__ unsigned short f2bf(float f) {
    union { float f; uint32_t i; } v; v.f = f;
    uint32_t r = v.i + 0x7FFFu + ((v.i >> 16) & 1u);  // RNE
    return (unsigned short)(r >> 16);
}
// async 16B global->LDS (dest = wave-uniform base + lane*16). imm offset ALWAYS 0.
__device__ __forceinline__ void cp16(const unsigned short* g, unsigned short* l) {
    __builtin_amdgcn_global_load_lds(
        (const __attribute__((address_space(1))) uint32_t*)g,
        (__attribute__((address_space(3))) uint32_t*)l, 16, 0, 0);
}

// ---- weight transpose + fp32->bf16 (round-0 verbatim: measured-fast shape).
//      NOTE round-10 lesson: do NOT merge this with the router — per-block
//      ticket/fence at 6500+-block scale serializes (~95 us/block). ----
__global__ __launch_bounds__(256)
void k_transpose(const float* __restrict__ eg, const float* __restrict__ eu,
                 const float* __restrict__ ed, const float* __restrict__ sg,
                 const float* __restrict__ su, const float* __restrict__ sd,
                 unsigned short* __restrict__ Wgu, unsigned short* __restrict__ Wd)
{
    int z = blockIdx.z;
    int e = z / 3, m = z % 3;
    int R = (m == 2) ? 512 : 1024;   // src rows (k)
    int C = (m == 2) ? 1024 : 512;   // src cols (n)
    int r0 = blockIdx.y * 64, c0 = blockIdx.x * 64;
    if (r0 >= R || c0 >= C) return;
    const float* src;
    if (m == 0)      src = (e < 16) ? eg + (size_t)e * 524288 : sg;
    else if (m == 1) src = (e < 16) ? eu + (size_t)e * 524288 : su;
    else             src = (e < 16) ? ed + (size_t)e * 524288 : sd;

    __shared__ float tl[64 * 65];
    const int tid = threadIdx.x;

    {
        const int lr = tid >> 4;          // 0..15
        const int lc = (tid & 15) * 4;    // 0..60
        #pragma unroll
        for (int ps = 0; ps < 4; ++ps) {
            int r = ps * 16 + lr;
            float4 v = *(const float4*)(src + (size_t)(r0 + r) * C + (c0 + lc));
            float* d = &tl[r * 65 + lc];
            d[0] = v.x; d[1] = v.y; d[2] = v.z; d[3] = v.w;
        }
    }
    __syncthreads();

    {
        const int w = tid >> 6, l = tid & 63;
        const int kb = (l & 7) * 8;       // k-chunk within tile (8 elems = 16 B)
        #pragma unroll
        for (int p = 0; p < 2; ++p) {
            int nl = p * 32 + w * 8 + (l >> 3);
            unsigned short ov[8];
            #pragma unroll
            for (int j = 0; j < 8; ++j)
                ov[j] = f2bf(tl[(kb + j) * 65 + nl]);
            int n = c0 + nl;
            int k = r0 + kb;
            unsigned short* dst;
            if (m < 2) dst = Wgu + (size_t)e * 1048576 + (size_t)(2 * n + m) * 1024 + k;
            else       dst = Wd  + (size_t)e * 524288  + (size_t)n * 512 + k;
            *(uint4*)dst = *(uint4*)ov;
        }
    }
}

// ---- fused route (round-8 measured-good): xconv + router (stride-13 LDS,
//      conflict-free) + 512-block ticket prefix, now also emitting mytab. ----
__global__ __launch_bounds__(512, 3)
void k_route(const float* __restrict__ x, const float* __restrict__ gw,
             const float* __restrict__ gb, unsigned short* __restrict__ xb,
             int* __restrict__ tok, int2* __restrict__ rec,
             float2* __restrict__ wrec, int* __restrict__ counts,
             int* __restrict__ bases, int4* __restrict__ mytab)
{
    __shared__ float gws[1024 * 13];             // 53248 B (pad 13: conflict-free)
    __shared__ int pfx[40];                      // winner: bases [0..17], mbp [20..37]
    __shared__ int winflag;

    const int bid = blockIdx.x;
    const int tid = threadIdx.x;

    // ---- fused xconv: this block's 8 token rows (2048 float4 groups) ----
    {
        const int b0 = bid * 2048;
        #pragma unroll
        for (int c = 0; c < 4; ++c) {
            int i = b0 + c * 512 + tid;
            float4 v = ((const float4*)x)[i];
            ushort4 b;
            b.x = f2bf(v.x); b.y = f2bf(v.y); b.z = f2bf(v.z); b.w = f2bf(v.w);
            ((ushort4*)xb)[i] = b;
        }
        if (tid < 8) tok[16 * 4096 + bid * 8 + tid] = bid * 8 + tid;
    }

    const int t = bid * 8 + (tid >> 6);
    const int lane = tid & 63;
    const float* xr = x + (size_t)t * DDIM;

    float xv[16];
    #pragma unroll
    for (int kk = 0; kk < 16; ++kk) xv[kk] = xr[kk * 64 + lane];

    float v[16];

    for (int p = 0; p < 2; ++p) {
        __syncthreads();
        #pragma unroll
        for (int c = 0; c < 4; ++c) {
            int idx = tid + c * 512;             // 0..2047
            int k = idx >> 1;
            int h = (idx & 1) * 4;               // 0 or 4 floats
            float4 g4 = *(const float4*)(gw + k * 16 + p * 8 + h);
            *(float4*)&gws[k * 13 + h] = g4;
        }
        __syncthreads();

        double a[8];
        #pragma unroll
        for (int j = 0; j < 8; ++j) a[j] = 0.0;

        #pragma unroll
        for (int kk = 0; kk < 16; ++kk) {
            int kl = kk * 64 + lane;
            float4 gA = *(const float4*)&gws[kl * 13];
            float4 gB = *(const float4*)&gws[kl * 13 + 4];
            double xd = (double)xv[kk];
            a[0] += xd * (double)gA.x; a[1] += xd * (double)gA.y;
            a[2] += xd * (double)gA.z; a[3] += xd * (double)gA.w;
            a[4] += xd * (double)gB.x; a[5] += xd * (double)gB.y;
            a[6] += xd * (double)gB.z; a[7] += xd * (double)gB.w;
        }

        #pragma unroll
        for (int off = 32; off > 0; off >>= 1) {
            #pragma unroll
            for (int j = 0; j < 8; ++j)
                a[j] += __shfl_xor(a[j], off, 64);
        }

        #pragma unroll
        for (int j = 0; j < 8; ++j)
            v[p * 8 + j] = 1.0f / (1.0f + expf(-(float)(a[j] + (double)gb[p * 8 + j])));
    }

    if (lane == 0) {
        int i0 = 0;
        #pragma unroll
        for (int e = 1; e < 16; ++e) if (v[e] > v[i0]) i0 = e;
        int i1 = (i0 == 0) ? 1 : 0;
        #pragma unroll
        for (int e = 0; e < 16; ++e) if (e != i0 && e != i1 && v[e] > v[i1]) i1 = e;
        float s = v[i0] + v[i1];
        float w0 = v[i0] / s, w1 = v[i1] / s;
        int p0 = atomicAdd(&counts[i0 * CSTRIDE], 1);   // padded: 1 line per expert
        tok[i0 * 4096 + p0] = t;
        int p1 = atomicAdd(&counts[i1 * CSTRIDE], 1);
        tok[i1 * 4096 + p1] = t;
        rec[t]  = make_int2(i0 * 4096 + p0, i1 * 4096 + p1);
        wrec[t] = make_float2(w0, w1);
    }

    // ---- ticket (512 blocks: measured-safe scale): winner builds bases + mytab ----
    __syncthreads();
    if (tid == 0) {
        __threadfence();
        winflag = (atomicAdd(&counts[TICKET_IDX], 1) == (int)gridDim.x - 1) ? 1 : 0;
    }
    __syncthreads();
    if (winflag) {
        if (tid == 0) {
            int a = 0, b = 0;
            for (int e2 = 0; e2 < NEXP1; ++e2) {
                int c = (e2 < 16) ? atomicAdd(&counts[e2 * CSTRIDE], 0) : TOKENS;
                pfx[e2] = a; pfx[20 + e2] = b;
                bases[e2] = a;                   // combine needs global bases
                a += c; b += (c + 127) >> 7;
            }
            pfx[17] = a; pfx[37] = b;
            bases[17] = a;
        }
        __syncthreads();
        const int nmb = pfx[37];
        for (int idx = tid; idx < MAXMB; idx += 512) {
            int4 val = make_int4(0, 0, 0, 0);    // cnt=0,m0=0 -> gemm exits
            if (idx < nmb) {
                int e2 = 0;
                #pragma unroll
                for (int i2 = 1; i2 <= 16; ++i2)
                    if (idx >= pfx[20 + i2]) e2 = i2;
                val = make_int4(e2, (idx - pfx[20 + e2]) * 128,
                                pfx[e2], pfx[e2 + 1] - pfx[e2]);
            }
            mytab[idx] = val;
        }
    }
}

// ---- grouped GEMM: round-0 core + round-8 zero-conflict seg swizzle (measured
//      53.3 us) + mytab one-load lookup (verified r10) + XCD swizzle (T1). ----
// MODE 0: A = xb gathered, K=1024, B = Wgu interleaved -> fused silu -> H (bf16)
// MODE 1: A = H (contiguous slots), K=512, B = Wd -> Hgu (bf16)
template <int MODE>
__global__ __launch_bounds__(256, 3)
void k_gemm(const unsigned short* __restrict__ Amat, const unsigned short* __restrict__ Bmat,
            const int* __restrict__ tok, const int4* __restrict__ mytab,
            unsigned short* __restrict__ Out)
{
    constexpr int K = (MODE == 0) ? 1024 : 512;
    // XCD swizzle: lin%8 = XCD; each XCD gets 14 consecutive m-blocks x all 8 N.
    const int lin = blockIdx.x;                     // 0..895 (8*112)
    const int wg  = (lin & 7) * MAXMB + (lin >> 3);
    const int my  = wg >> 3;
    const int n0  = (wg & 7) * 128;
    const int4 tt = mytab[my];
    const int e = tt.x, m0 = tt.y, base = tt.z, cnt = tt.w;
    if (m0 >= cnt) return;

    __shared__ unsigned short As0[128 * 32];   // k-half 0 (8 KB each, 64-B rows)
    __shared__ unsigned short As1[128 * 32];   // k-half 1
    __shared__ unsigned short Bs0[128 * 32];
    __shared__ unsigned short Bs1[128 * 32];

    const int tid  = threadIdx.x;
    const int wave = tid >> 6;
    const int lane = tid & 63;
    const int lrow = lane >> 2;                          // 0..15
    const int lseg = (lane & 3) ^ ((lrow >> 1) & 3);     // swizzled source 16B segment

    unsigned short* a0d0 = &As0[wave * 1024];
    unsigned short* a0d1 = &As0[wave * 1024 + 512];
    unsigned short* a1d0 = &As1[wave * 1024];
    unsigned short* a1d1 = &As1[wave * 1024 + 512];
    unsigned short* b0d0 = &Bs0[wave * 1024];
    unsigned short* b0d1 = &Bs0[wave * 1024 + 512];
    unsigned short* b1d0 = &Bs1[wave * 1024];
    unsigned short* b1d1 = &Bs1[wave * 1024 + 512];

    int ar0 = m0 + wave * 32 + lrow;      if (ar0 > cnt - 1) ar0 = cnt - 1;
    int ar1 = m0 + wave * 32 + 16 + lrow; if (ar1 > cnt - 1) ar1 = cnt - 1;
    size_t ai0, ai1;
    if (MODE == 0) { ai0 = (size_t)tok[e * 4096 + ar0]; ai1 = (size_t)tok[e * 4096 + ar1]; }
    else           { ai0 = (size_t)(base + ar0);        ai1 = (size_t)(base + ar1); }
    const unsigned short* ag0 = Amat + ai0 * K + lseg * 8;
    const unsigned short* ag1 = Amat + ai1 * K + lseg * 8;
    const size_t eoff = (size_t)e * 1024 * K;
    const unsigned short* bg0 = Bmat + eoff + (size_t)(n0 + wave * 32 + lrow) * K + lseg * 8;
    const unsigned short* bg1 = Bmat + eoff + (size_t)(n0 + wave * 32 + 16 + lrow) * K + lseg * 8;

    const int wm = wave & 1, wn = wave >> 1;
    const int q = lane >> 4, mc = lane & 15;
    const int qs = (q ^ ((mc >> 1) & 3)) * 8;            // swizzled read seg (elems)

    f32x4 acc[4][4];
    #pragma unroll
    for (int i = 0; i < 4; ++i)
        #pragma unroll
        for (int j = 0; j < 4; ++j) acc[i][j] = (f32x4){0.f, 0.f, 0.f, 0.f};

    for (int k0 = 0; k0 < K; k0 += 64) {
        __syncthreads();
        cp16(ag0 + k0,      a0d0);
        cp16(ag0 + k0 + 32, a1d0);
        cp16(ag1 + k0,      a0d1);
        cp16(ag1 + k0 + 32, a1d1);
        cp16(bg0 + k0,      b0d0);
        cp16(bg0 + k0 + 32, b1d0);
        cp16(bg1 + k0,      b0d1);
        cp16(bg1 + k0 + 32, b1d1);
        __syncthreads();
        short8 a0[4], b0[4], a1[4], b1[4];
        #pragma unroll
        for (int i = 0; i < 4; ++i) {
            a0[i] = *(const short8*)&As0[(wm * 64 + i * 16 + mc) * 32 + qs];
            a1[i] = *(const short8*)&As1[(wm * 64 + i * 16 + mc) * 32 + qs];
        }
        #pragma unroll
        for (int j = 0; j < 4; ++j) {
            b0[j] = *(const short8*)&Bs0[(wn * 64 + j * 16 + mc) * 32 + qs];
            b1[j] = *(const short8*)&Bs1[(wn * 64 + j * 16 + mc) * 32 + qs];
        }
        #pragma unroll
        for (int i = 0; i < 4; ++i)
            #pragma unroll
            for (int j = 0; j < 4; ++j)
                acc[i][j] = __builtin_amdgcn_mfma_f32_16x16x32_bf16(a0[i], b0[j], acc[i][j], 0, 0, 0);
        #pragma unroll
        for (int i = 0; i < 4; ++i)
            #pragma unroll
            for (int j = 0; j < 4; ++j)
                acc[i][j] = __builtin_amdgcn_mfma_f32_16x16x32_bf16(a1[i], b1[j], acc[i][j], 0, 0, 0);
    }

    // epilogue: C/D layout col=lane&15, row=(lane>>4)*4+reg  [m89-verified]
    #pragma unroll
    for (int i = 0; i < 4; ++i) {
        int lr = wm * 64 + i * 16 + q * 4;
        #pragma unroll
        for (int r = 0; r < 4; ++r) {
            int mrow = m0 + lr + r;
            if (mrow >= cnt) continue;
            #pragma unroll
            for (int j = 0; j < 4; ++j) {
                int gc = n0 + wn * 64 + j * 16 + mc;
                float val = acc[i][j][r];
                if (MODE == 0) {
                    float other = __shfl_xor(val, 1, 64);
                    float g = (mc & 1) ? other : val;
                    float u = (mc & 1) ? val : other;
                    float h = g / (1.0f + __expf(-g)) * u;
                    if ((mc & 1) == 0)
                        Out[(size_t)(base + mrow) * 512 + (gc >> 1)] = f2bf(h);
                } else {
                    Out[(size_t)(base + mrow) * 1024 + gc] = f2bf(val);
                }
            }
        }
    }
}

// ---- out[t] = x[t] + Hs[shared] + w0*Hs[s0] + w1*Hs[s1] ----
__global__ void k_combine(const float* __restrict__ x, const unsigned short* __restrict__ Hs,
                          const int2* __restrict__ rec, const float2* __restrict__ wrec,
                          const int* __restrict__ bases, float* __restrict__ out)
{
    int t = blockIdx.x * 2 + (threadIdx.x >> 7);
    int c = (threadIdx.x & 127) * 8;
    int2 r = rec[t];
    float2 w = wrec[t];
    int s0 = bases[r.x >> 12] + (r.x & 4095);
    int s1 = bases[r.y >> 12] + (r.y & 4095);
    int ss = 8192 + t;

    unsigned short h0[8], h1[8], hs[8];
    *(uint4*)h0 = *(const uint4*)(Hs + (size_t)s0 * 1024 + c);
    *(uint4*)h1 = *(const uint4*)(Hs + (size_t)s1 * 1024 + c);
    *(uint4*)hs = *(const uint4*)(Hs + (size_t)ss * 1024 + c);
    const float* xr = x + (size_t)t * 1024 + c;
    float o[8];
    #pragma unroll
    for (int j = 0; j < 8; ++j)
        o[j] = xr[j] + bf2f(hs[j]) + w.x * bf2f(h0[j]) + w.y * bf2f(h1[j]);
    float* orow = out + (size_t)t * 1024 + c;
    *(float4*)orow       = *(float4*)&o[0];
    *(float4*)(orow + 4) = *(float4*)&o[4];
}

extern "C" void kernel_launch(void* const* d_in, const int* in_sizes, int n_in,
                              void* d_out, int out_size, void* d_ws, size_t ws_size,
                              hipStream_t stream)
{
    const float* x  = (const float*)d_in[0];
    const float* gw = (const float*)d_in[1];
    const float* gb = (const float*)d_in[2];
    const float* sg = (const float*)d_in[3];
    const float* su = (const float*)d_in[4];
    const float* sd = (const float*)d_in[5];
    const float* eg = (const float*)d_in[6];
    const float* eu = (const float*)d_in[7];
    const float* ed = (const float*)d_in[8];
    float* out = (float*)d_out;
    char* ws = (char*)d_ws;

    unsigned short* Wgu = (unsigned short*)(ws + OFF_WGU);
    unsigned short* Wd  = (unsigned short*)(ws + OFF_WD);
    unsigned short* xb  = (unsigned short*)(ws + OFF_XB);
    unsigned short* Hgu = (unsigned short*)(ws + OFF_HGU);
    unsigned short* H   = (unsigned short*)(ws + OFF_H);
    int*    tok   = (int*)(ws + OFF_TOK);
    int2*   rec   = (int2*)(ws + OFF_REC);
    float2* wrec  = (float2*)(ws + OFF_WREC);
    int4*   mytab = (int4*)(ws + OFF_MYTAB);
    int*    counts= (int*)(ws + OFF_CNT);
    int*    bases = (int*)(ws + OFF_BASE);

    (void)hipMemsetAsync(counts, 0, 4096, stream);
    k_transpose<<<dim3(16, 16, 51), 256, 0, stream>>>(eg, eu, ed, sg, su, sd, Wgu, Wd);
    k_route<<<512, 512, 0, stream>>>(x, gw, gb, xb, tok, rec, wrec, counts, bases, mytab);
    k_gemm<0><<<8 * MAXMB, 256, 0, stream>>>(xb, Wgu, tok, mytab, H);
    k_gemm<1><<<8 * MAXMB, 256, 0, stream>>>(H, Wd, tok, mytab, Hgu);
    k_combine<<<2048, 256, 0, stream>>>(x, Hgu, rec, wrec, bases, out);
}